// Round 1
// baseline (337.876 us; speedup 1.0000x reference)
//
#include <hip/hip_runtime.h>
#include <math.h>

// Problem constants
#define TOKENS 1024   // B*S = 2*512
#define DDIM   1024
#define NHEAD  8
#define QD     256
#define HQD    2048   // NHEAD*QD
#define NROWS  8192   // TOKENS*NHEAD
#define NKEY   128
#define NEXP   16384
#define TOPK   16
#define ODIM   1024

// ---------------------------------------------------------------------------
// K1: q = hidden @ Wq + bq   [1024,1024] x [1024,2048]  fp32 tiled GEMM
// tile 128(M) x 64(N), K-step 32, 256 threads, 8x4 outputs/thread
// ---------------------------------------------------------------------------
__global__ __launch_bounds__(256) void k_qproj(const float* __restrict__ A,
                                               const float* __restrict__ W,
                                               const float* __restrict__ bias,
                                               float* __restrict__ q)
{
    __shared__ float As[32][132];  // [k][m], padded
    __shared__ float Bs[32][68];   // [k][n], padded
    const int tid = threadIdx.x;
    const int m0 = blockIdx.y * 128;
    const int n0 = blockIdx.x * 64;
    const int aRow = tid >> 3;          // 0..31
    const int aK4  = (tid & 7) * 4;     // 0..28
    const int bRow = tid >> 4;          // 0..15
    const int bN4  = (tid & 15) * 4;    // 0..60
    const int ty = tid >> 4;            // 0..15 -> m = ty*8
    const int tx = tid & 15;            // 0..15 -> n = tx*4

    float acc[8][4] = {};

    for (int kk = 0; kk < DDIM; kk += 32) {
        __syncthreads();
#pragma unroll
        for (int p = 0; p < 4; p++) {
            int m = p * 32 + aRow;
            float4 v = *(const float4*)(A + (size_t)(m0 + m) * DDIM + kk + aK4);
            As[aK4][m] = v.x; As[aK4 + 1][m] = v.y;
            As[aK4 + 2][m] = v.z; As[aK4 + 3][m] = v.w;
        }
#pragma unroll
        for (int p = 0; p < 2; p++) {
            int k = p * 16 + bRow;
            float4 v = *(const float4*)(W + (size_t)(kk + k) * HQD + n0 + bN4);
            *(float4*)&Bs[k][bN4] = v;
        }
        __syncthreads();
#pragma unroll
        for (int k = 0; k < 32; k++) {
            float a[8], b[4];
            *(float4*)(a)     = *(const float4*)&As[k][ty * 8];
            *(float4*)(a + 4) = *(const float4*)&As[k][ty * 8 + 4];
            *(float4*)(b)     = *(const float4*)&Bs[k][tx * 4];
#pragma unroll
            for (int i = 0; i < 8; i++)
#pragma unroll
                for (int j = 0; j < 4; j++)
                    acc[i][j] = fmaf(a[i], b[j], acc[i][j]);
        }
    }

    float4 bv = *(const float4*)(bias + n0 + tx * 4);
#pragma unroll
    for (int i = 0; i < 8; i++) {
        int m = m0 + ty * 8 + i;
        float4 r;
        r.x = acc[i][0] + bv.x; r.y = acc[i][1] + bv.y;
        r.z = acc[i][2] + bv.z; r.w = acc[i][3] + bv.w;
        *(float4*)(q + (size_t)m * HQD + n0 + tx * 4) = r;
    }
}

// ---------------------------------------------------------------------------
// K2a: partial column sums/sumsq over q viewed as [8192][256]
// 64 blocks x 128 rows each; thread j handles column j
// ---------------------------------------------------------------------------
__global__ __launch_bounds__(256) void k_bnstat1(const float* __restrict__ q,
                                                 float* __restrict__ psum,
                                                 float* __restrict__ psq)
{
    const int b = blockIdx.x;   // 0..63
    const int j = threadIdx.x;  // 0..255
    const float* p = q + (size_t)b * 128 * 256 + j;
    float s = 0.f, sq = 0.f;
    for (int r = 0; r < 128; r++) {
        float v = p[(size_t)r * 256];
        s += v; sq += v * v;
    }
    psum[b * 256 + j] = s;
    psq[b * 256 + j]  = sq;
}

// K2b: finish stats -> mean[j], scale[j] = gamma/sqrt(var+eps)
__global__ __launch_bounds__(256) void k_bnstat2(const float* __restrict__ psum,
                                                 const float* __restrict__ psq,
                                                 const float* __restrict__ gamma,
                                                 float* __restrict__ meanOut,
                                                 float* __restrict__ scaleOut)
{
    const int j = threadIdx.x;
    float s = 0.f, sq = 0.f;
    for (int b = 0; b < 64; b++) {
        s += psum[b * 256 + j];
        sq += psq[b * 256 + j];
    }
    float mean = s * (1.0f / 8192.0f);
    float var = sq * (1.0f / 8192.0f) - mean * mean;
    meanOut[j] = mean;
    scaleOut[j] = gamma[j] / sqrtf(var + 1e-5f);
}

// ---------------------------------------------------------------------------
// K3: L2-normalize sub_key rows (256 rows total, 128 dims each)
// ---------------------------------------------------------------------------
__global__ __launch_bounds__(128) void k_keynorm(const float* __restrict__ k0,
                                                 const float* __restrict__ k1,
                                                 float* __restrict__ o0,
                                                 float* __restrict__ o1)
{
    const int b = blockIdx.x;               // 0..255
    const float* src = (b < 128) ? k0 : k1;
    float* dst = (b < 128) ? o0 : o1;
    const int row = b & 127;
    const int tid = threadIdx.x;            // 128 threads
    float v = src[row * 128 + tid];
    float sq = v * v;
    for (int off = 32; off; off >>= 1) sq += __shfl_down(sq, off);
    __shared__ float tmp[2];
    __shared__ float invs;
    if ((tid & 63) == 0) tmp[tid >> 6] = sq;
    __syncthreads();
    if (tid == 0) {
        float n = sqrtf(tmp[0] + tmp[1]);
        invs = 1.0f / fmaxf(n, 1e-12f);
    }
    __syncthreads();
    dst[row * 128 + tid] = v * invs;
}

// ---------------------------------------------------------------------------
// K4a: in-place BN transform + per-half L2 normalize of q rows [8192][256]
// one 64-thread wave per row; lanes 0..31 = half0 (j<128), 32..63 = half1
// ---------------------------------------------------------------------------
__global__ __launch_bounds__(64) void k_bnnorm(float* __restrict__ q,
                                               const float* __restrict__ mean,
                                               const float* __restrict__ scale,
                                               const float* __restrict__ beta)
{
    const int r = blockIdx.x;
    const int tid = threadIdx.x;  // 0..63
    const int j = tid * 4;
    float4 v = *(const float4*)(q + (size_t)r * 256 + j);
    float4 m = *(const float4*)(mean + j);
    float4 sc = *(const float4*)(scale + j);
    float4 be = *(const float4*)(beta + j);
    float x0 = (v.x - m.x) * sc.x + be.x;
    float x1 = (v.y - m.y) * sc.y + be.y;
    float x2 = (v.z - m.z) * sc.z + be.z;
    float x3 = (v.w - m.w) * sc.w + be.w;
    float sq = x0 * x0 + x1 * x1 + x2 * x2 + x3 * x3;
    // reduce within each 32-lane half
    for (int off = 16; off; off >>= 1) sq += __shfl_xor(sq, off);
    float inv = 1.0f / fmaxf(sqrtf(sq), 1e-12f);
    x0 *= inv; x1 *= inv; x2 *= inv; x3 *= inv;
    float4 o; o.x = x0; o.y = x1; o.z = x2; o.w = x3;
    *(float4*)(q + (size_t)r * 256 + j) = o;
}

// ---------------------------------------------------------------------------
// K4b: scores s_half[8192][128] = qn_half [8192][128] @ keys_half^T [128][128]
// block: 64 rows x 128 keys, d chunked by 64. grid (128 tiles, 2 halves)
// ---------------------------------------------------------------------------
__global__ __launch_bounds__(256) void k_scores(const float* __restrict__ q,
                                                const float* __restrict__ kn0,
                                                const float* __restrict__ kn1,
                                                float* __restrict__ sOut0,
                                                float* __restrict__ sOut1)
{
    __shared__ float Ks[64][132];  // [d][n]
    __shared__ float Qs[64][68];   // [d][r]
    const int half = blockIdx.y;
    const int row0 = blockIdx.x * 64;
    const float* kn = half ? kn1 : kn0;
    float* sOut = half ? sOut1 : sOut0;
    const int tid = threadIdx.x;
    const int ty = tid >> 5;   // 0..7  -> r = ty*8
    const int tx = tid & 31;   // 0..31 -> n = tx*4
    float acc[8][4] = {};

    for (int c = 0; c < 2; c++) {
        __syncthreads();
        {
            int d4 = (tid & 15) * 4;
            int n = tid >> 4;  // 0..15
#pragma unroll
            for (int p = 0; p < 8; p++) {
                int nn = n + p * 16;
                float4 v = *(const float4*)(kn + nn * 128 + c * 64 + d4);
                Ks[d4][nn] = v.x; Ks[d4 + 1][nn] = v.y;
                Ks[d4 + 2][nn] = v.z; Ks[d4 + 3][nn] = v.w;
            }
            int r = tid >> 4;
#pragma unroll
            for (int p = 0; p < 4; p++) {
                int rr = r + p * 16;
                float4 v = *(const float4*)(q + (size_t)(row0 + rr) * 256 + half * 128 + c * 64 + d4);
                Qs[d4][rr] = v.x; Qs[d4 + 1][rr] = v.y;
                Qs[d4 + 2][rr] = v.z; Qs[d4 + 3][rr] = v.w;
            }
        }
        __syncthreads();
#pragma unroll
        for (int d = 0; d < 64; d++) {
            float a[8], b[4];
            *(float4*)(a)     = *(const float4*)&Qs[d][ty * 8];
            *(float4*)(a + 4) = *(const float4*)&Qs[d][ty * 8 + 4];
            *(float4*)(b)     = *(const float4*)&Ks[d][tx * 4];
#pragma unroll
            for (int i = 0; i < 8; i++)
#pragma unroll
                for (int j = 0; j < 4; j++)
                    acc[i][j] = fmaf(a[i], b[j], acc[i][j]);
        }
    }
#pragma unroll
    for (int i = 0; i < 8; i++) {
        float4 r;
        r.x = acc[i][0]; r.y = acc[i][1]; r.z = acc[i][2]; r.w = acc[i][3];
        *(float4*)(sOut + (size_t)(row0 + ty * 8 + i) * 128 + tx * 4) = r;
    }
}

// ---------------------------------------------------------------------------
// K4c: per (token,head) row: exact top-16 of cartesian sum + softmax.
// Rank-by-counting reproduces jax.lax.top_k ordering (value desc, index asc)
// exactly, including ties. Candidates = top16(s0) x top16(s1) provably
// contain the true top-16 under that total order.
// ---------------------------------------------------------------------------
__global__ __launch_bounds__(256) void k_topk(const float* __restrict__ s0,
                                              const float* __restrict__ s1,
                                              int* __restrict__ tIdx,
                                              float* __restrict__ tW)
{
    __shared__ float sv[256];
    __shared__ float hv[2][16];
    __shared__ int   hi[2][16];
    __shared__ float cv[256];
    __shared__ int   ci[256];
    __shared__ float selv[16];
    __shared__ int   seli[16];
    const int row = blockIdx.x;
    const int tid = threadIdx.x;

    sv[tid] = (tid < 128) ? s0[(size_t)row * 128 + tid]
                          : s1[(size_t)row * 128 + tid - 128];
    __syncthreads();
    {
        const int hsel = tid >> 7;          // 0 or 1
        const int base = hsel << 7;
        const int i = tid - base;
        const float v = sv[tid];
        int rank = 0;
        for (int j = 0; j < 128; j++) {
            float u = sv[base + j];
            rank += (u > v) || (u == v && j < i);
        }
        if (rank < 16) { hv[hsel][rank] = v; hi[hsel][rank] = i; }
    }
    __syncthreads();
    {
        cv[tid] = hv[0][tid >> 4] + hv[1][tid & 15];
        ci[tid] = hi[0][tid >> 4] * 128 + hi[1][tid & 15];
    }
    __syncthreads();
    {
        const float v = cv[tid];
        const int idx = ci[tid];
        int rank = 0;
        for (int j = 0; j < 256; j++) {
            float u = cv[j];
            rank += (u > v) || (u == v && ci[j] < idx);
        }
        if (rank < 16) { selv[rank] = v; seli[rank] = idx; }
    }
    __syncthreads();
    if (tid < 16) {
        float m = selv[0];  // rank 0 = max
        float e = expf(selv[tid] - m);
        float s = e;
        for (int off = 8; off; off >>= 1) s += __shfl_xor(s, off);
        tW[(size_t)row * 16 + tid] = e / s;
        tIdx[(size_t)row * 16 + tid] = seli[tid];
    }
}

// ---------------------------------------------------------------------------
// K5: per token: 128 expert dots (down . hidden) -> gelu -> weighted sum of
// expert_up rows into out[token].
// ---------------------------------------------------------------------------
__global__ __launch_bounds__(256) void k_expert(const float* __restrict__ hidden,
                                                const float* __restrict__ down,
                                                const float* __restrict__ up,
                                                const int* __restrict__ tIdx,
                                                const float* __restrict__ tW,
                                                float* __restrict__ out)
{
    __shared__ float hs[1024];
    __shared__ float coef[128];
    __shared__ int   eidx[128];
    __shared__ float wv[128];
    const int t = blockIdx.x;
    const int tid = threadIdx.x;

    *(float4*)(hs + tid * 4) = *(const float4*)(hidden + (size_t)t * 1024 + tid * 4);
    if (tid < 128) {
        eidx[tid] = tIdx[(size_t)t * 128 + tid];
        wv[tid]   = tW[(size_t)t * 128 + tid];
    }
    __syncthreads();

    const int wave = tid >> 6, lane = tid & 63;
    for (int i = 0; i < 32; i++) {
        const int p = wave * 32 + i;
        const float4* dp = (const float4*)(down + (size_t)eidx[p] * 1024);
        float sum = 0.f;
#pragma unroll
        for (int c = 0; c < 4; c++) {
            float4 dv = dp[lane + 64 * c];
            float4 hv4 = *(const float4*)(hs + (lane + 64 * c) * 4);
            sum += dv.x * hv4.x + dv.y * hv4.y + dv.z * hv4.z + dv.w * hv4.w;
        }
        for (int off = 32; off; off >>= 1) sum += __shfl_down(sum, off);
        if (lane == 0) {
            float x = sum;
            float g = 0.5f * x * (1.0f + erff(x * 0.70710678118654752f));
            coef[p] = wv[p] * g;
        }
    }
    __syncthreads();

    float4 acc = make_float4(0.f, 0.f, 0.f, 0.f);
#pragma unroll 4
    for (int p = 0; p < 128; p++) {
        float c = coef[p];
        float4 u = *(const float4*)(up + (size_t)eidx[p] * 1024 + tid * 4);
        acc.x += c * u.x; acc.y += c * u.y;
        acc.z += c * u.z; acc.w += c * u.w;
    }
    *(float4*)(out + (size_t)t * 1024 + tid * 4) = acc;
}

// ---------------------------------------------------------------------------
extern "C" void kernel_launch(void* const* d_in, const int* in_sizes, int n_in,
                              void* d_out, int out_size, void* d_ws, size_t ws_size,
                              hipStream_t stream)
{
    const float* hidden = (const float*)d_in[0];
    const float* Wq     = (const float*)d_in[1];
    const float* bq     = (const float*)d_in[2];
    const float* gamma  = (const float*)d_in[3];
    const float* beta   = (const float*)d_in[4];
    const float* sk0    = (const float*)d_in[5];
    const float* sk1    = (const float*)d_in[6];
    const float* down   = (const float*)d_in[7];
    const float* up     = (const float*)d_in[8];
    float* out = (float*)d_out;

    float* ws = (float*)d_ws;
    size_t o = 0;
    float* q     = ws + o; o += (size_t)TOKENS * HQD;      // 2,097,152
    float* ps    = ws + o; o += 64 * 256;                  // 16,384
    float* pq    = ws + o; o += 64 * 256;                  // 16,384
    float* meanb = ws + o; o += 256;
    float* scaleb= ws + o; o += 256;
    float* k0n   = ws + o; o += NKEY * 128;                // 16,384
    float* k1n   = ws + o; o += NKEY * 128;                // 16,384
    float* s0    = ws + o; o += (size_t)NROWS * 128;       // 1,048,576
    float* s1    = ws + o; o += (size_t)NROWS * 128;       // 1,048,576
    float* tW    = ws + o; o += (size_t)NROWS * TOPK;      // 131,072
    int*   tIdx  = (int*)(ws + o); o += (size_t)NROWS * TOPK;

    k_qproj <<<dim3(32, 8), 256, 0, stream>>>(hidden, Wq, bq, q);
    k_bnstat1<<<64, 256, 0, stream>>>(q, ps, pq);
    k_bnstat2<<<1, 256, 0, stream>>>(ps, pq, gamma, meanb, scaleb);
    k_keynorm<<<256, 128, 0, stream>>>(sk0, sk1, k0n, k1n);
    k_bnnorm <<<NROWS, 64, 0, stream>>>(q, meanb, scaleb, beta);
    k_scores <<<dim3(128, 2), 256, 0, stream>>>(q, k0n, k1n, s0, s1);
    k_topk   <<<NROWS, 256, 0, stream>>>(s0, s1, tIdx, tW);
    k_expert <<<TOKENS, 256, 0, stream>>>(hidden, down, up, tIdx, tW, out);
}

// Round 2
// 284.189 us; speedup vs baseline: 1.1889x; 1.1889x over previous
//
#include <hip/hip_runtime.h>
#include <math.h>

typedef unsigned long long u64;
typedef unsigned int u32;

// Problem constants
#define TOKENS 1024   // B*S = 2*512
#define DDIM   1024
#define NHEAD  8
#define QD     256
#define HQD    2048   // NHEAD*QD
#define NROWS  8192   // TOKENS*NHEAD
#define NKEY   128
#define TOPK   16

// ---------------------------------------------------------------------------
// K1: q = hidden @ Wq + bq   [1024,1024] x [1024,2048]  fp32 tiled GEMM
// tile 64(M) x 64(N), K-step 32, 256 threads, 4x4 outputs/thread
// grid 32x16 = 512 blocks -> 2 blocks/CU, 8 waves/CU
// ---------------------------------------------------------------------------
__global__ __launch_bounds__(256) void k_qproj(const float* __restrict__ A,
                                               const float* __restrict__ W,
                                               const float* __restrict__ bias,
                                               float* __restrict__ q)
{
    __shared__ float As[32][68];  // [k][m], padded
    __shared__ float Bs[32][68];  // [k][n], padded
    const int tid = threadIdx.x;
    const int m0 = blockIdx.y * 64;
    const int n0 = blockIdx.x * 64;
    const int aM  = tid >> 3;           // 0..31
    const int aK4 = (tid & 7) * 4;      // 0..28
    const int bK  = tid >> 4;           // 0..15
    const int bN4 = (tid & 15) * 4;     // 0..60
    const int ty = tid >> 4;            // 0..15 -> m = ty*4
    const int tx = tid & 15;            // 0..15 -> n = tx*4

    float acc[4][4] = {};

    for (int kk = 0; kk < DDIM; kk += 32) {
        __syncthreads();
#pragma unroll
        for (int p = 0; p < 2; p++) {
            int m = aM + 32 * p;
            float4 v = *(const float4*)(A + (size_t)(m0 + m) * DDIM + kk + aK4);
            As[aK4][m] = v.x; As[aK4 + 1][m] = v.y;
            As[aK4 + 2][m] = v.z; As[aK4 + 3][m] = v.w;
        }
#pragma unroll
        for (int p = 0; p < 2; p++) {
            int k = bK + 16 * p;
            float4 v = *(const float4*)(W + (size_t)(kk + k) * HQD + n0 + bN4);
            *(float4*)&Bs[k][bN4] = v;
        }
        __syncthreads();
#pragma unroll
        for (int k = 0; k < 32; k++) {
            float a[4], b[4];
            *(float4*)(a) = *(const float4*)&As[k][ty * 4];
            *(float4*)(b) = *(const float4*)&Bs[k][tx * 4];
#pragma unroll
            for (int i = 0; i < 4; i++)
#pragma unroll
                for (int j = 0; j < 4; j++)
                    acc[i][j] = fmaf(a[i], b[j], acc[i][j]);
        }
    }

    float4 bv = *(const float4*)(bias + n0 + tx * 4);
#pragma unroll
    for (int i = 0; i < 4; i++) {
        int m = m0 + ty * 4 + i;
        float4 r;
        r.x = acc[i][0] + bv.x; r.y = acc[i][1] + bv.y;
        r.z = acc[i][2] + bv.z; r.w = acc[i][3] + bv.w;
        *(float4*)(q + (size_t)m * HQD + n0 + tx * 4) = r;
    }
}

// ---------------------------------------------------------------------------
// K2a: partial column sums/sumsq over q viewed as [8192][256]
// ---------------------------------------------------------------------------
__global__ __launch_bounds__(256) void k_bnstat1(const float* __restrict__ q,
                                                 float* __restrict__ psum,
                                                 float* __restrict__ psq)
{
    const int b = blockIdx.x;   // 0..63
    const int j = threadIdx.x;  // 0..255
    const float* p = q + (size_t)b * 128 * 256 + j;
    float s = 0.f, sq = 0.f;
    for (int r = 0; r < 128; r++) {
        float v = p[(size_t)r * 256];
        s += v; sq += v * v;
    }
    psum[b * 256 + j] = s;
    psq[b * 256 + j]  = sq;
}

// K2b: finish stats -> mean[j], scale[j] = gamma/sqrt(var+eps)
__global__ __launch_bounds__(256) void k_bnstat2(const float* __restrict__ psum,
                                                 const float* __restrict__ psq,
                                                 const float* __restrict__ gamma,
                                                 float* __restrict__ meanOut,
                                                 float* __restrict__ scaleOut)
{
    const int j = threadIdx.x;
    float s = 0.f, sq = 0.f;
    for (int b = 0; b < 64; b++) {
        s += psum[b * 256 + j];
        sq += psq[b * 256 + j];
    }
    float mean = s * (1.0f / 8192.0f);
    float var = sq * (1.0f / 8192.0f) - mean * mean;
    meanOut[j] = mean;
    scaleOut[j] = gamma[j] / sqrtf(var + 1e-5f);
}

// ---------------------------------------------------------------------------
// K3: L2-normalize sub_key rows (256 rows total, 128 dims each)
// ---------------------------------------------------------------------------
__global__ __launch_bounds__(128) void k_keynorm(const float* __restrict__ k0,
                                                 const float* __restrict__ k1,
                                                 float* __restrict__ o0,
                                                 float* __restrict__ o1)
{
    const int b = blockIdx.x;               // 0..255
    const float* src = (b < 128) ? k0 : k1;
    float* dst = (b < 128) ? o0 : o1;
    const int row = b & 127;
    const int tid = threadIdx.x;            // 128 threads
    float v = src[row * 128 + tid];
    float sq = v * v;
    for (int off = 32; off; off >>= 1) sq += __shfl_down(sq, off);
    __shared__ float tmp[2];
    __shared__ float invs;
    if ((tid & 63) == 0) tmp[tid >> 6] = sq;
    __syncthreads();
    if (tid == 0) {
        float n = sqrtf(tmp[0] + tmp[1]);
        invs = 1.0f / fmaxf(n, 1e-12f);
    }
    __syncthreads();
    dst[row * 128 + tid] = v * invs;
}

// ---------------------------------------------------------------------------
// K4a: in-place BN transform + per-half L2 normalize of q rows [8192][256]
// one wave per row, 4 rows/block
// ---------------------------------------------------------------------------
__global__ __launch_bounds__(256) void k_bnnorm(float* __restrict__ q,
                                                const float* __restrict__ mean,
                                                const float* __restrict__ scale,
                                                const float* __restrict__ beta)
{
    const int r = blockIdx.x * 4 + (threadIdx.x >> 6);
    const int lane = threadIdx.x & 63;
    const int j = lane * 4;
    float4 v = *(const float4*)(q + (size_t)r * 256 + j);
    float4 m = *(const float4*)(mean + j);
    float4 sc = *(const float4*)(scale + j);
    float4 be = *(const float4*)(beta + j);
    float x0 = (v.x - m.x) * sc.x + be.x;
    float x1 = (v.y - m.y) * sc.y + be.y;
    float x2 = (v.z - m.z) * sc.z + be.z;
    float x3 = (v.w - m.w) * sc.w + be.w;
    float sq = x0 * x0 + x1 * x1 + x2 * x2 + x3 * x3;
    // reduce within each 32-lane half (halves of the 256-dim row)
    for (int off = 16; off; off >>= 1) sq += __shfl_xor(sq, off);
    float inv = 1.0f / fmaxf(sqrtf(sq), 1e-12f);
    x0 *= inv; x1 *= inv; x2 *= inv; x3 *= inv;
    float4 o; o.x = x0; o.y = x1; o.z = x2; o.w = x3;
    *(float4*)(q + (size_t)r * 256 + j) = o;
}

// ---------------------------------------------------------------------------
// K4b: scores s_half[8192][128] = qn_half [8192][128] @ keys_half^T
// ---------------------------------------------------------------------------
__global__ __launch_bounds__(256) void k_scores(const float* __restrict__ q,
                                                const float* __restrict__ kn0,
                                                const float* __restrict__ kn1,
                                                float* __restrict__ sOut0,
                                                float* __restrict__ sOut1)
{
    __shared__ float Ks[64][132];  // [d][n]
    __shared__ float Qs[64][68];   // [d][r]
    const int half = blockIdx.y;
    const int row0 = blockIdx.x * 64;
    const float* kn = half ? kn1 : kn0;
    float* sOut = half ? sOut1 : sOut0;
    const int tid = threadIdx.x;
    const int ty = tid >> 5;   // 0..7  -> r = ty*8
    const int tx = tid & 31;   // 0..31 -> n = tx*4
    float acc[8][4] = {};

    for (int c = 0; c < 2; c++) {
        __syncthreads();
        {
            int d4 = (tid & 15) * 4;
            int n = tid >> 4;  // 0..15
#pragma unroll
            for (int p = 0; p < 8; p++) {
                int nn = n + p * 16;
                float4 v = *(const float4*)(kn + nn * 128 + c * 64 + d4);
                Ks[d4][nn] = v.x; Ks[d4 + 1][nn] = v.y;
                Ks[d4 + 2][nn] = v.z; Ks[d4 + 3][nn] = v.w;
            }
            int r = tid >> 4;
#pragma unroll
            for (int p = 0; p < 4; p++) {
                int rr = r + p * 16;
                float4 v = *(const float4*)(q + (size_t)(row0 + rr) * 256 + half * 128 + c * 64 + d4);
                Qs[d4][rr] = v.x; Qs[d4 + 1][rr] = v.y;
                Qs[d4 + 2][rr] = v.z; Qs[d4 + 3][rr] = v.w;
            }
        }
        __syncthreads();
#pragma unroll
        for (int d = 0; d < 64; d++) {
            float a[8], b[4];
            *(float4*)(a)     = *(const float4*)&Qs[d][ty * 8];
            *(float4*)(a + 4) = *(const float4*)&Qs[d][ty * 8 + 4];
            *(float4*)(b)     = *(const float4*)&Ks[d][tx * 4];
#pragma unroll
            for (int i = 0; i < 8; i++)
#pragma unroll
                for (int j = 0; j < 4; j++)
                    acc[i][j] = fmaf(a[i], b[j], acc[i][j]);
        }
    }
#pragma unroll
    for (int i = 0; i < 8; i++) {
        float4 r;
        r.x = acc[i][0]; r.y = acc[i][1]; r.z = acc[i][2]; r.w = acc[i][3];
        *(float4*)(sOut + (size_t)(row0 + ty * 8 + i) * 128 + tx * 4) = r;
    }
}

// ---------------------------------------------------------------------------
// K4c: per (token,head) row: exact top-16 + softmax via iterative extraction.
// One wave per row; packed u64 keys reproduce (value desc, index asc) order.
// ---------------------------------------------------------------------------
__device__ __forceinline__ u64 mkkey(float v, u32 idx) {
    u32 ub = __float_as_uint(v);
    ub = (ub & 0x80000000u) ? ~ub : (ub | 0x80000000u);  // order-preserving map
    return ((u64)ub << 32) | (u64)(0xFFFFFFFFu - idx);
}
__device__ __forceinline__ float keyval(u64 k) {
    u32 ub = (u32)(k >> 32);
    u32 fb = (ub & 0x80000000u) ? (ub ^ 0x80000000u) : ~ub;
    return __uint_as_float(fb);
}
__device__ __forceinline__ u32 keyidx(u64 k) {
    return 0xFFFFFFFFu - (u32)(k & 0xFFFFFFFFu);
}

__global__ __launch_bounds__(256) void k_topk(const float* __restrict__ s0,
                                              const float* __restrict__ s1,
                                              int* __restrict__ tIdx,
                                              float* __restrict__ tW)
{
    __shared__ float shv[4][2][16];
    __shared__ int   shi[4][2][16];
    const int w = threadIdx.x >> 6;
    const int lane = threadIdx.x & 63;
    const int row = blockIdx.x * 4 + w;

    // ---- per-half top-16 (16 extractions, 64-lane butterfly max on u64 keys)
#pragma unroll
    for (int h = 0; h < 2; h++) {
        const float* s = h ? s1 : s0;
        float v0 = s[(size_t)row * 128 + lane];
        float v1 = s[(size_t)row * 128 + 64 + lane];
        u64 k0 = mkkey(v0, (u32)lane);
        u64 k1 = mkkey(v1, (u32)(lane + 64));
        for (int r = 0; r < 16; r++) {
            u64 m = (k0 > k1) ? k0 : k1;
#pragma unroll
            for (int off = 1; off < 64; off <<= 1) {
                u64 o = __shfl_xor(m, off);
                if (o > m) m = o;
            }
            if (k0 == m) k0 = 0;
            if (k1 == m) k1 = 0;
            if (lane == 0) { shv[w][h][r] = keyval(m); shi[w][h][r] = (int)keyidx(m); }
        }
    }
    // wave-private LDS (no cross-wave sharing): in-order LDS pipeline suffices

    // ---- cartesian 256 candidates, extract top-16
    u64 ck[4];
#pragma unroll
    for (int qq = 0; qq < 4; qq++) {
        int id = lane + 64 * qq;
        int a = id >> 4, b = id & 15;
        float v = shv[w][0][a] + shv[w][1][b];
        u32 idx = (u32)(shi[w][0][a] * 128 + shi[w][1][b]);
        ck[qq] = mkkey(v, idx);
    }
    float winv = 0.f; u32 wini = 0;
    for (int r = 0; r < 16; r++) {
        u64 m = ck[0];
#pragma unroll
        for (int qq = 1; qq < 4; qq++) if (ck[qq] > m) m = ck[qq];
#pragma unroll
        for (int off = 1; off < 64; off <<= 1) {
            u64 o = __shfl_xor(m, off);
            if (o > m) m = o;
        }
#pragma unroll
        for (int qq = 0; qq < 4; qq++) if (ck[qq] == m) ck[qq] = 0;
        if (lane == r) { winv = keyval(m); wini = keyidx(m); }
    }
    // ---- softmax over the 16 winners (lanes 0..15 hold ranks 0..15)
    float vmax = __shfl(winv, 0);
    if (lane < 16) {
        float e = expf(winv - vmax);
        float ssum = e;
#pragma unroll
        for (int off = 1; off < 16; off <<= 1) ssum += __shfl_xor(ssum, off, 16);
        tW[(size_t)row * 16 + lane] = e / ssum;
        tIdx[(size_t)row * 16 + lane] = (int)wini;
    }
}

// ---------------------------------------------------------------------------
// K5a: coef[t][p] = w[p] * gelu(down[e_p] . hidden[t])
// one block per token, 16 waves; wave handles 8 experts
// ---------------------------------------------------------------------------
__global__ __launch_bounds__(1024) void k_coef(const float* __restrict__ hidden,
                                               const float* __restrict__ down,
                                               const int* __restrict__ tIdx,
                                               const float* __restrict__ tW,
                                               float* __restrict__ coef)
{
    __shared__ __align__(16) float hs[1024];
    __shared__ int   eidx[128];
    __shared__ float wv[128];
    const int t = blockIdx.x;
    const int tid = threadIdx.x;  // 0..1023

    hs[tid] = hidden[(size_t)t * 1024 + tid];
    if (tid < 128) {
        eidx[tid] = tIdx[(size_t)t * 128 + tid];
        wv[tid]   = tW[(size_t)t * 128 + tid];
    }
    __syncthreads();

    const int wave = tid >> 6, lane = tid & 63;
#pragma unroll 2
    for (int i = 0; i < 8; i++) {
        const int p = wave * 8 + i;
        const float4* dp = (const float4*)(down + (size_t)eidx[p] * 1024);
        float sum = 0.f;
#pragma unroll
        for (int c = 0; c < 4; c++) {
            float4 dv = dp[lane + 64 * c];
            float4 hv = *(const float4*)(hs + (lane + 64 * c) * 4);
            sum += dv.x * hv.x + dv.y * hv.y + dv.z * hv.z + dv.w * hv.w;
        }
        for (int off = 32; off; off >>= 1) sum += __shfl_down(sum, off);
        if (lane == 0) {
            float x = sum;
            float g = 0.5f * x * (1.0f + erff(x * 0.70710678118654752f));
            coef[(size_t)t * 128 + p] = wv[p] * g;
        }
    }
}

// ---------------------------------------------------------------------------
// K5b: out[t][j] = sum_p coef[t][p] * up[e_p][j]
// grid = token x 4 chunks of 256 outputs; 128 independent scalar gathers/thread
// ---------------------------------------------------------------------------
__global__ __launch_bounds__(256) void k_accum(const float* __restrict__ up,
                                               const int* __restrict__ tIdx,
                                               const float* __restrict__ coef,
                                               float* __restrict__ out)
{
    __shared__ float cf[128];
    __shared__ int   ei[128];
    const int t = blockIdx.x >> 2;
    const int c = blockIdx.x & 3;
    const int tid = threadIdx.x;
    if (tid < 128) {
        cf[tid] = coef[(size_t)t * 128 + tid];
        ei[tid] = tIdx[(size_t)t * 128 + tid];
    }
    __syncthreads();
    const int j = c * 256 + tid;
    float acc = 0.f;
#pragma unroll 8
    for (int p = 0; p < 128; p++)
        acc = fmaf(cf[p], up[(size_t)ei[p] * 1024 + j], acc);
    out[(size_t)t * 1024 + j] = acc;
}

// ---------------------------------------------------------------------------
extern "C" void kernel_launch(void* const* d_in, const int* in_sizes, int n_in,
                              void* d_out, int out_size, void* d_ws, size_t ws_size,
                              hipStream_t stream)
{
    const float* hidden = (const float*)d_in[0];
    const float* Wq     = (const float*)d_in[1];
    const float* bq     = (const float*)d_in[2];
    const float* gamma  = (const float*)d_in[3];
    const float* beta   = (const float*)d_in[4];
    const float* sk0    = (const float*)d_in[5];
    const float* sk1    = (const float*)d_in[6];
    const float* down   = (const float*)d_in[7];
    const float* up     = (const float*)d_in[8];
    float* out = (float*)d_out;

    float* ws = (float*)d_ws;
    size_t o = 0;
    float* q     = ws + o; o += (size_t)TOKENS * HQD;      // 2,097,152
    float* ps    = ws + o; o += 64 * 256;
    float* pq    = ws + o; o += 64 * 256;
    float* meanb = ws + o; o += 256;
    float* scaleb= ws + o; o += 256;
    float* k0n   = ws + o; o += NKEY * 128;
    float* k1n   = ws + o; o += NKEY * 128;
    float* s0    = ws + o; o += (size_t)NROWS * 128;
    float* s1    = ws + o; o += (size_t)NROWS * 128;
    float* tW    = ws + o; o += (size_t)NROWS * TOPK;
    int*   tIdx  = (int*)(ws + o); o += (size_t)NROWS * TOPK;
    float* coef  = ws + o; o += (size_t)TOKENS * 128;

    k_qproj  <<<dim3(32, 16), 256, 0, stream>>>(hidden, Wq, bq, q);
    k_bnstat1<<<64, 256, 0, stream>>>(q, ps, pq);
    k_bnstat2<<<1, 256, 0, stream>>>(ps, pq, gamma, meanb, scaleb);
    k_keynorm<<<256, 128, 0, stream>>>(sk0, sk1, k0n, k1n);
    k_bnnorm <<<2048, 256, 0, stream>>>(q, meanb, scaleb, beta);
    k_scores <<<dim3(128, 2), 256, 0, stream>>>(q, k0n, k1n, s0, s1);
    k_topk   <<<2048, 256, 0, stream>>>(s0, s1, tIdx, tW);
    k_coef   <<<TOKENS, 1024, 0, stream>>>(hidden, down, tIdx, tW, coef);
    k_accum  <<<4096, 256, 0, stream>>>(up, tIdx, coef, out);
}